// Round 4
// baseline (92.611 us; speedup 1.0000x reference)
//
#include <hip/hip_runtime.h>
#include <hip/hip_bf16.h>

typedef __attribute__((ext_vector_type(8))) short s8v;            // 8 x bf16
typedef __attribute__((ext_vector_type(8))) unsigned short u8v;   // 8 x u16
typedef __attribute__((ext_vector_type(4))) float f4v;            // 4 x f32

__device__ __forceinline__ short f2bf(float f) {
    __hip_bfloat16 h = __float2bfloat16(f);
    union { __hip_bfloat16 h; short s; } u{h};
    return u.s;
}
__device__ __forceinline__ float bf2f(unsigned short v) {
    union { unsigned u; float f; } x; x.u = ((unsigned)v) << 16; return x.f;
}

// ---------------------------------------------------------------------------
// prep kernel: blocks [0,1024) do winner atomicMax; blocks [1024,1064) pack
// the four weight matrices into bf16 B-fragment order for mfma_16x16x32_bf16:
//   frag f = ks*8+n; lane l holds W[ks*32+(l>>4)*8+e][n*16+(l&15)], e=0..7.
// ---------------------------------------------------------------------------
__global__ void prep_kernel(const int* __restrict__ nr, const int* __restrict__ nc,
                            int* __restrict__ win,
                            const float* __restrict__ w1c, const float* __restrict__ w2c,
                            const float* __restrict__ w1f, const float* __restrict__ w2f,
                            short* __restrict__ p1c, short* __restrict__ p2c,
                            short* __restrict__ p1f, short* __restrict__ p2f)
{
    int b = blockIdx.x, t = threadIdx.x;
    if (b < 1024) {                       // winner: 1024*256 = 262144 indices
        int i = b * 256 + t;
        atomicMax(&win[nr[i] * 32 + nc[i]], i);
        return;
    }
    int id = (b - 1024) * 256 + t;        // 40*256 = 10240 = 160 frags * 64 lanes
    int f  = id >> 6, l = id & 63;
    const float* W; short* P; int fl;
    if      (f < 64)  { W = w1c; P = p1c; fl = f; }        // K=256: 64 frags
    else if (f < 96)  { W = w2c; P = p2c; fl = f - 64; }   // K=128: 32 frags
    else if (f < 128) { W = w1f; P = p1f; fl = f - 96; }
    else              { W = w2f; P = p2f; fl = f - 128; }
    int g = l >> 4, c = l & 15;
    int ks = fl >> 3, n = fl & 7;
    s8v o;
    #pragma unroll
    for (int e = 0; e < 8; ++e)
        o[e] = f2bf(W[(ks*32 + g*8 + e) * 128 + n*16 + c]);
    *(s8v*)(P + ((fl*64 + l) << 3)) = o;
}

// ---------------------------------------------------------------------------
// Fused MFMA MLP: out = relu(LN2(LN1(X@W1)@W2)) [+ fused scatter when FINE]
// 256 threads = 4 waves; 64 rows/block; each wave owns 16 rows.
// Epilogue re-staged through per-wave LDS for fully coalesced global I/O.
// ---------------------------------------------------------------------------
template<int K1, bool FINE>
__global__ __launch_bounds__(256, 4)
void mlp_mfma(const float* __restrict__ X,
              const short* __restrict__ Wp1,
              const float* __restrict__ g1v, const float* __restrict__ b1v,
              const short* __restrict__ Wp2,
              const float* __restrict__ g2v, const float* __restrict__ b2v,
              float* __restrict__ outF,            // FINE: f32 output
              unsigned short* __restrict__ outB,   // !FINE: bf16 fc output
              const int* __restrict__ winner,
              const unsigned short* __restrict__ fcB)
{
    __shared__ short H1L[4][16][136];   // per-wave 16x128 bf16, pitch 136 shorts

    const int t = threadIdx.x;
    const int wave = t >> 6, lane = t & 63;
    const int g = lane >> 4, c = lane & 15;
    const int wrow = blockIdx.x * 64 + wave * 16;

    // prefetch winner early: lane l holds winner for row (l&15); latency hides
    // under the whole MLP body.
    int wv = 0;
    if constexpr (FINE) wv = winner[wrow + c];

    // preload LN params
    float G1[8], B1[8], G2[8], B2[8];
    #pragma unroll
    for (int n = 0; n < 8; ++n) {
        G1[n] = g1v[n*16 + c]; B1[n] = b1v[n*16 + c];
        G2[n] = g2v[n*16 + c]; B2[n] = b2v[n*16 + c];
    }

    // ---------- Layer 1: H1 = X @ W1 (1-deep pipelined A loads) ----------
    f4v acc[8];
    #pragma unroll
    for (int n = 0; n < 8; ++n) acc[n] = (f4v){0.f, 0.f, 0.f, 0.f};

    const float* pa = X + (size_t)(wrow + c) * K1 + g*8;
    float4 a0 = *(const float4*)pa;
    float4 a1 = *(const float4*)(pa + 4);
    #pragma unroll
    for (int ks = 0; ks < K1/32; ++ks) {
        float4 c0 = a0, c1 = a1;
        if (ks + 1 < K1/32) {
            a0 = *(const float4*)(pa + (ks+1)*32);
            a1 = *(const float4*)(pa + (ks+1)*32 + 4);
        }
        s8v af;
        af[0] = f2bf(c0.x); af[1] = f2bf(c0.y); af[2] = f2bf(c0.z); af[3] = f2bf(c0.w);
        af[4] = f2bf(c1.x); af[5] = f2bf(c1.y); af[6] = f2bf(c1.z); af[7] = f2bf(c1.w);
        #pragma unroll
        for (int n = 0; n < 8; ++n) {
            s8v bf = *(const s8v*)(Wp1 + (((ks*8 + n)*64 + lane) << 3));
            acc[n] = __builtin_amdgcn_mfma_f32_16x16x32_bf16(af, bf, acc[n], 0, 0, 0);
        }
    }

    // ---------- LN1 (in-register, 16-lane groups) -> LDS bf16 (XOR swizzle) ----------
    #pragma unroll
    for (int j = 0; j < 4; ++j) {
        float sm = 0.f, sq = 0.f;
        #pragma unroll
        for (int n = 0; n < 8; ++n) { float v = acc[n][j]; sm += v; sq += v*v; }
        #pragma unroll
        for (int m = 1; m < 16; m <<= 1) {
            sm += __shfl_xor(sm, m, 64);
            sq += __shfl_xor(sq, m, 64);
        }
        float mean = sm * (1.f/128.f);
        float rstd = rsqrtf(sq * (1.f/128.f) - mean*mean + 1e-5f);
        int row = g*4 + j;
        #pragma unroll
        for (int n = 0; n < 8; ++n) {
            float y = (acc[n][j] - mean) * rstd * G1[n] + B1[n];
            H1L[wave][row][(n*16 + c) ^ (g << 3)] = f2bf(y);
        }
    }

    // ---------- Layer 2: H2 = H1 @ W2 (A-frags via swizzled ds_read_b128) ----------
    f4v acc2[8];
    #pragma unroll
    for (int n = 0; n < 8; ++n) acc2[n] = (f4v){0.f, 0.f, 0.f, 0.f};

    const int rg = (c >> 2) & 3;
    #pragma unroll
    for (int ks = 0; ks < 4; ++ks) {
        s8v af = *(const s8v*)&H1L[wave][c][(ks*32 + g*8) ^ (rg << 3)];
        #pragma unroll
        for (int n = 0; n < 8; ++n) {
            s8v bf = *(const s8v*)(Wp2 + (((ks*8 + n)*64 + lane) << 3));
            acc2[n] = __builtin_amdgcn_mfma_f32_16x16x32_bf16(af, bf, acc2[n], 0, 0, 0);
        }
    }

    // ---------- LN2 + ReLU -> LDS (same swizzle) ----------
    #pragma unroll
    for (int j = 0; j < 4; ++j) {
        float sm = 0.f, sq = 0.f;
        #pragma unroll
        for (int n = 0; n < 8; ++n) { float v = acc2[n][j]; sm += v; sq += v*v; }
        #pragma unroll
        for (int m = 1; m < 16; m <<= 1) {
            sm += __shfl_xor(sm, m, 64);
            sq += __shfl_xor(sq, m, 64);
        }
        float mean = sm * (1.f/128.f);
        float rstd = rsqrtf(sq * (1.f/128.f) - mean*mean + 1e-5f);
        int row = g*4 + j;
        #pragma unroll
        for (int n = 0; n < 8; ++n) {
            float y = fmaxf((acc2[n][j] - mean) * rstd * G2[n] + B2[n], 0.f);
            H1L[wave][row][(n*16 + c) ^ (g << 3)] = f2bf(y);
        }
    }

    // ---------- coalesced writeback (per-wave LDS, no barrier needed) ----------
    // row = it*4 + (lane>>4); writer of row had g_w = row>>2 = it, so the
    // physical col8 is (c8 ^ it) (xor on bits >=3 keeps 8-short contiguity).
    const int c8 = lane & 15;
    #pragma unroll
    for (int it = 0; it < 4; ++it) {
        int row = it*4 + (lane >> 4);
        int R   = wrow + row;
        s8v v = *(const s8v*)&H1L[wave][row][(c8 ^ it) * 8];
        if constexpr (FINE) {
            float y8[8];
            #pragma unroll
            for (int e = 0; e < 8; ++e) y8[e] = bf2f((unsigned short)v[e]);
            int w = __shfl(wv, row, 64);
            if (w >= 0) {
                const u8v u = *(const u8v*)(fcB + (size_t)(w & 32767) * 128 + c8*8);
                #pragma unroll
                for (int e = 0; e < 8; ++e) y8[e] += bf2f(u[e]);
            }
            float4 o0 = {y8[0], y8[1], y8[2], y8[3]};
            float4 o1 = {y8[4], y8[5], y8[6], y8[7]};
            float* op = outF + (size_t)R * 128 + c8*8;
            *(float4*)op       = o0;
            *(float4*)(op + 4) = o1;
        } else {
            *(s8v*)(outB + (size_t)R * 128 + c8*8) = v;
        }
    }
}

extern "C" void kernel_launch(void* const* d_in, const int* in_sizes, int n_in,
                              void* d_out, int out_size, void* d_ws, size_t ws_size,
                              hipStream_t stream)
{
    const float* fcoarse = (const float*)d_in[0];
    const float* ffine   = (const float*)d_in[1];
    const float* w1c = (const float*)d_in[2];
    const float* g1c = (const float*)d_in[3];
    const float* b1c = (const float*)d_in[4];
    const float* w2c = (const float*)d_in[5];
    const float* g2c = (const float*)d_in[6];
    const float* b2c = (const float*)d_in[7];
    const float* w1f = (const float*)d_in[8];
    const float* g1f = (const float*)d_in[9];
    const float* b1f = (const float*)d_in[10];
    const float* w2f = (const float*)d_in[11];
    const float* g2f = (const float*)d_in[12];
    const float* b2f = (const float*)d_in[13];
    const int* nrow  = (const int*)d_in[14];
    const int* ncol  = (const int*)d_in[15];

    float* out = (float*)d_out;

    const int Mc = 32768, Mf = 131072;

    // workspace: fcB (bf16, 8MB) | winner (512KB) | packed weights (160KB)
    unsigned short* fcB = (unsigned short*)d_ws;
    char* base = (char*)d_ws;
    int*   winner = (int*)(base + 8u*1024*1024);
    short* p1c = (short*)(base + 8u*1024*1024 + 512u*1024);
    short* p2c = p1c + 256*128;
    short* p1f = p2c + 128*128;
    short* p2f = p1f + 128*128;

    hipMemsetAsync(winner, 0xFF, (size_t)Mf * sizeof(int), stream);
    // winner resolution (1024 blocks) + weight packing (40 blocks)
    prep_kernel<<<1064, 256, 0, stream>>>(nrow, ncol, winner,
                                          w1c, w2c, w1f, w2f,
                                          p1c, p2c, p1f, p2f);

    // coarse MLP -> fcB (bf16)
    mlp_mfma<256, false><<<Mc/64, 256, 0, stream>>>(fcoarse, p1c, g1c, b1c,
                                                    p2c, g2c, b2c,
                                                    nullptr, fcB, nullptr, nullptr);
    // fine MLP + fused scatter -> out
    mlp_mfma<128, true><<<Mf/64, 256, 0, stream>>>(ffine, p1f, g1f, b1f,
                                                   p2f, g2f, b2f,
                                                   out, nullptr, winner, fcB);
}

// Round 5
// 81.036 us; speedup vs baseline: 1.1428x; 1.1428x over previous
//
#include <hip/hip_runtime.h>
#include <hip/hip_bf16.h>

typedef __attribute__((ext_vector_type(8))) short s8v;            // 8 x bf16
typedef __attribute__((ext_vector_type(4))) float f4v;            // 4 x f32

__device__ __forceinline__ short f2bf(float f) {
    __hip_bfloat16 h = __float2bfloat16(f);
    union { __hip_bfloat16 h; short s; } u{h};
    return u.s;
}
__device__ __forceinline__ float bf2f(unsigned short v) {
    union { unsigned u; float f; } x; x.u = ((unsigned)v) << 16; return x.f;
}

// ---------------------------------------------------------------------------
// pack kernel: pack the four weight matrices into bf16 B-fragment order for
// mfma_16x16x32_bf16: frag f = ks*8+n; lane l holds
// W[ks*32+(l>>4)*8+e][n*16+(l&15)], e=0..7.   40 blocks x 256 thr.
// ---------------------------------------------------------------------------
__global__ void pack_kernel(const float* __restrict__ w1c, const float* __restrict__ w2c,
                            const float* __restrict__ w1f, const float* __restrict__ w2f,
                            short* __restrict__ p1c, short* __restrict__ p2c,
                            short* __restrict__ p1f, short* __restrict__ p2f)
{
    int id = blockIdx.x * 256 + threadIdx.x;   // 10240 = 160 frags * 64 lanes
    int f  = id >> 6, l = id & 63;
    const float* W; short* P; int fl;
    if      (f < 64)  { W = w1c; P = p1c; fl = f; }        // K=256: 64 frags
    else if (f < 96)  { W = w2c; P = p2c; fl = f - 64; }   // K=128: 32 frags
    else if (f < 128) { W = w1f; P = p1f; fl = f - 96; }
    else              { W = w2f; P = p2f; fl = f - 128; }
    int g = l >> 4, c = l & 15;
    int ks = fl >> 3, n = fl & 7;
    s8v o;
    #pragma unroll
    for (int e = 0; e < 8; ++e)
        o[e] = f2bf(W[(ks*32 + g*8 + e) * 128 + n*16 + c]);
    *(s8v*)(P + ((fl*64 + l) << 3)) = o;
}

// ---------------------------------------------------------------------------
// Fused MFMA MLP: out = relu(LN2(LN1(X@W1)@W2)) [+ fused scatter when FINE]
// 256 threads = 4 waves; 64 rows/block; each wave owns 16 rows.
// When NWIN>0, the first NWIN blocks instead do winner atomicMax resolution
// (backfills CUs while the small coarse grid runs).
// ---------------------------------------------------------------------------
template<int K1, bool FINE>
__global__ __launch_bounds__(256, 4)
void mlp_mfma(const float* __restrict__ X,
              const short* __restrict__ Wp1,
              const float* __restrict__ g1v, const float* __restrict__ b1v,
              const short* __restrict__ Wp2,
              const float* __restrict__ g2v, const float* __restrict__ b2v,
              float* __restrict__ outF,            // FINE: f32 output
              unsigned short* __restrict__ outB,   // !FINE: bf16 fc output
              const int* __restrict__ winner,
              const unsigned short* __restrict__ fcB,
              const int* __restrict__ nr, const int* __restrict__ nc,
              int* __restrict__ win, int nWinBlocks)
{
    // per-wave 16x128 bf16 slice, NO pad; 16B-granule XOR-row swizzle.
    __shared__ short H[4][16][128];   // 16 KB

    if (blockIdx.x < (unsigned)nWinBlocks) {      // winner-resolution blocks
        int i = blockIdx.x * 256 + threadIdx.x;   // nWinBlocks*256 indices
        atomicMax(&win[nr[i] * 32 + nc[i]], i);
        return;
    }
    const int bid = blockIdx.x - nWinBlocks;

    const int t = threadIdx.x;
    const int wave = t >> 6, lane = t & 63;
    const int g = lane >> 4, c = lane & 15;
    const int wrow = bid * 64 + wave * 16;

    // prefetch winner early (lane l holds winner for row l&15)
    int wv = 0;
    if constexpr (FINE) wv = winner[wrow + c];

    float G1[8], B1[8];
    #pragma unroll
    for (int n = 0; n < 8; ++n) { G1[n] = g1v[n*16 + c]; B1[n] = b1v[n*16 + c]; }

    // ---------- Layer 1: H1 = X @ W1 (batched weight loads, pipelined A) ----
    f4v acc[8];
    #pragma unroll
    for (int n = 0; n < 8; ++n) acc[n] = (f4v){0.f, 0.f, 0.f, 0.f};

    const float* pa = X + (size_t)(wrow + c) * K1 + g*8;
    const short* wp1 = Wp1 + (lane << 3);
    float4 a0 = *(const float4*)pa;
    float4 a1 = *(const float4*)(pa + 4);
    #pragma unroll
    for (int ks = 0; ks < K1/32; ++ks) {
        s8v bfr[8];
        #pragma unroll
        for (int n = 0; n < 8; ++n)
            bfr[n] = *(const s8v*)(wp1 + ((ks*8 + n) << 9));
        s8v af;
        af[0] = f2bf(a0.x); af[1] = f2bf(a0.y); af[2] = f2bf(a0.z); af[3] = f2bf(a0.w);
        af[4] = f2bf(a1.x); af[5] = f2bf(a1.y); af[6] = f2bf(a1.z); af[7] = f2bf(a1.w);
        if (ks + 1 < K1/32) {
            a0 = *(const float4*)(pa + (ks+1)*32);
            a1 = *(const float4*)(pa + (ks+1)*32 + 4);
        }
        #pragma unroll
        for (int n = 0; n < 8; ++n)
            acc[n] = __builtin_amdgcn_mfma_f32_16x16x32_bf16(af, bfr[n], acc[n], 0, 0, 0);
    }

    // ---------- LN1 -> LDS (granule-XOR swizzle) ----------
    #pragma unroll
    for (int j = 0; j < 4; ++j) {
        float sm = 0.f, sq = 0.f;
        #pragma unroll
        for (int n = 0; n < 8; ++n) { float v = acc[n][j]; sm += v; sq += v*v; }
        #pragma unroll
        for (int m = 1; m < 16; m <<= 1) {
            sm += __shfl_xor(sm, m, 64);
            sq += __shfl_xor(sq, m, 64);
        }
        float mean = sm * (1.f/128.f);
        float rstd = rsqrtf(sq * (1.f/128.f) - mean*mean + 1e-5f);
        int row = g*4 + j;
        #pragma unroll
        for (int n = 0; n < 8; ++n) {
            float y = (acc[n][j] - mean) * rstd * G1[n] + B1[n];
            int col = n*16 + c;
            int phys = (((col >> 3) ^ row) << 3) | (col & 7);
            H[wave][row][phys] = f2bf(y);
        }
    }

    // ---------- Layer 2: H2 = H1 @ W2 (swizzled ds_read_b128, batched W) ----
    f4v acc2[8];
    #pragma unroll
    for (int n = 0; n < 8; ++n) acc2[n] = (f4v){0.f, 0.f, 0.f, 0.f};

    const short* wp2 = Wp2 + (lane << 3);
    #pragma unroll
    for (int ks = 0; ks < 4; ++ks) {
        s8v bfr[8];
        #pragma unroll
        for (int n = 0; n < 8; ++n)
            bfr[n] = *(const s8v*)(wp2 + ((ks*8 + n) << 9));
        s8v af = *(const s8v*)&H[wave][c][((ks*4 + g) ^ c) << 3];
        #pragma unroll
        for (int n = 0; n < 8; ++n)
            acc2[n] = __builtin_amdgcn_mfma_f32_16x16x32_bf16(af, bfr[n], acc2[n], 0, 0, 0);
    }

    // ---------- LN2 + ReLU + (FINE: gather-add) + direct store ----------
    float G2[8], B2[8];
    #pragma unroll
    for (int n = 0; n < 8; ++n) { G2[n] = g2v[n*16 + c]; B2[n] = b2v[n*16 + c]; }
    #pragma unroll
    for (int j = 0; j < 4; ++j) {
        float sm = 0.f, sq = 0.f;
        #pragma unroll
        for (int n = 0; n < 8; ++n) { float v = acc2[n][j]; sm += v; sq += v*v; }
        #pragma unroll
        for (int m = 1; m < 16; m <<= 1) {
            sm += __shfl_xor(sm, m, 64);
            sq += __shfl_xor(sq, m, 64);
        }
        float mean = sm * (1.f/128.f);
        float rstd = rsqrtf(sq * (1.f/128.f) - mean*mean + 1e-5f);
        int R = wrow + g*4 + j;
        float y[8];
        #pragma unroll
        for (int n = 0; n < 8; ++n)
            y[n] = fmaxf((acc2[n][j] - mean) * rstd * G2[n] + B2[n], 0.f);
        if constexpr (FINE) {
            int w = __shfl(wv, g*4 + j, 64);
            if (w >= 0) {
                const unsigned short* fp = fcB + (size_t)(w & 32767) * 128 + c;
                #pragma unroll
                for (int n = 0; n < 8; ++n) y[n] += bf2f(fp[n*16]);
            }
            float* op = outF + (size_t)R * 128 + c;
            #pragma unroll
            for (int n = 0; n < 8; ++n) op[n*16] = y[n];
        } else {
            unsigned short* op = outB + (size_t)R * 128 + c;
            #pragma unroll
            for (int n = 0; n < 8; ++n) op[n*16] = (unsigned short)f2bf(y[n]);
        }
    }
}

extern "C" void kernel_launch(void* const* d_in, const int* in_sizes, int n_in,
                              void* d_out, int out_size, void* d_ws, size_t ws_size,
                              hipStream_t stream)
{
    const float* fcoarse = (const float*)d_in[0];
    const float* ffine   = (const float*)d_in[1];
    const float* w1c = (const float*)d_in[2];
    const float* g1c = (const float*)d_in[3];
    const float* b1c = (const float*)d_in[4];
    const float* w2c = (const float*)d_in[5];
    const float* g2c = (const float*)d_in[6];
    const float* b2c = (const float*)d_in[7];
    const float* w1f = (const float*)d_in[8];
    const float* g1f = (const float*)d_in[9];
    const float* b1f = (const float*)d_in[10];
    const float* w2f = (const float*)d_in[11];
    const float* g2f = (const float*)d_in[12];
    const float* b2f = (const float*)d_in[13];
    const int* nrow  = (const int*)d_in[14];
    const int* ncol  = (const int*)d_in[15];

    float* out = (float*)d_out;

    const int Mc = 32768, Mf = 131072;

    // workspace: fcB (bf16, 8MB) | winner (512KB) | packed weights (160KB)
    unsigned short* fcB = (unsigned short*)d_ws;
    char* base = (char*)d_ws;
    int*   winner = (int*)(base + 8u*1024*1024);
    short* p1c = (short*)(base + 8u*1024*1024 + 512u*1024);
    short* p2c = p1c + 256*128;
    short* p1f = p2c + 128*128;
    short* p2f = p1f + 128*128;

    hipMemsetAsync(winner, 0xFF, (size_t)Mf * sizeof(int), stream);
    pack_kernel<<<40, 256, 0, stream>>>(w1c, w2c, w1f, w2f, p1c, p2c, p1f, p2f);

    // coarse MLP (512 blocks) + winner resolution (1024 blocks) in one dispatch
    mlp_mfma<256, false><<<1024 + Mc/64, 256, 0, stream>>>(
        fcoarse, p1c, g1c, b1c, p2c, g2c, b2c,
        nullptr, fcB, nullptr, nullptr,
        nrow, ncol, winner, 1024);

    // fine MLP + fused scatter -> out
    mlp_mfma<128, true><<<Mf/64, 256, 0, stream>>>(
        ffine, p1f, g1f, b1f, p2f, g2f, b2f,
        out, nullptr, winner, fcB,
        nullptr, nullptr, nullptr, 0);
}